// Round 8
// baseline (357.085 us; speedup 1.0000x reference)
//
#include <hip/hip_runtime.h>
#include <math.h>

#define BATCH 8
#define CH    256
#define NPIX  4096
#define CKDIM 64

typedef __attribute__((ext_vector_type(8))) short short8;   // 8 bf16 (4 VGPRs)
typedef __attribute__((ext_vector_type(4))) float f32x4;    // MFMA accumulator

#define MFMA16x16(a, b, c) __builtin_amdgcn_mfma_f32_16x16x32_bf16((a), (b), (c), 0, 0, 0)

__device__ __forceinline__ unsigned short f2bf(float f) {
    union { float f; unsigned int u; } v; v.f = f;
    unsigned int u = v.u;
    u += 0x7fffu + ((u >> 16) & 1u);      // round-to-nearest-even
    return (unsigned short)(u >> 16);
}

// ---------------------------------------------------------------------------
// Kernel P: build W_frag in MFMA-FRAGMENT order + bias_all[384].
// Element (o,c) of the logical W_all[384][256] lands at
//   idx = (((og*4 + w)*8 + kc)*64 + quad*16 + col)*8 + e
// with og=o>>6, w=(o>>4)&3, col=o&15, kc=c>>5, quad=(c>>3)&3, e=c&7 --
// so qkvf's per-wave A-operand load is ONE COALESCED 1KB line (was a
// 16-way-strided gather, the proven same-iter-latency poison pattern).
// ---------------------------------------------------------------------------
__global__ void prep_kernel(const float* __restrict__ wq, const float* __restrict__ bq,
                            const float* __restrict__ wk, const float* __restrict__ bk,
                            const float* __restrict__ wv, const float* __restrict__ bv,
                            const float* __restrict__ wg,
                            unsigned short* __restrict__ W_frag, float* __restrict__ bias_all) {
    int o = blockIdx.x;
    int c = threadIdx.x;

    float val;
    if (o < 64) {
        val = wq[o * CH + c];
        if (c == 0) bias_all[o] = bq[o];
    } else if (o < 128) {
        int oo = o - 64;
        val = wk[oo * CH + c];
        if (c == 0) bias_all[o] = bk[oo];
    } else {
        __shared__ float wgr[CH];
        int oo = o - 128;
        wgr[c] = wg[oo * CH + c];
        __syncthreads();
        float a0 = 0.f, a1 = 0.f, a2 = 0.f, a3 = 0.f;
#pragma unroll 4
        for (int m = 0; m < CH; m += 4) {
            a0 += wgr[m + 0] * wv[(m + 0) * CH + c];
            a1 += wgr[m + 1] * wv[(m + 1) * CH + c];
            a2 += wgr[m + 2] * wv[(m + 2) * CH + c];
            a3 += wgr[m + 3] * wv[(m + 3) * CH + c];
        }
        val = (a0 + a1) + (a2 + a3);
        if (c == 0) {
            float b = 0.f;
            for (int m = 0; m < CH; ++m) b += wgr[m] * bv[m];
            bias_all[o] = b;
        }
    }

    int og = o >> 6, w = (o >> 4) & 3, col = o & 15;
    int kc = c >> 5, quad = (c >> 3) & 3, e = c & 7;
    size_t idx = ((size_t)(((og * 4 + w) * 8 + kc) * 64 + quad * 16 + col)) * 8 + e;
    W_frag[idx] = f2bf(val);
}

// ---------------------------------------------------------------------------
// Kernel G': FUSED xpose+qkv. W A-operands now read via the fragment layout
// (coalesced 1KB/wave lines, L2-hot). 3 blocks/CU (LDS 49.3KB x3 fits).
// ---------------------------------------------------------------------------
__global__ __launch_bounds__(256, 3)
void qkvf_mfma(const float* __restrict__ x,
               const unsigned short* __restrict__ W_frag,
               const float* __restrict__ bias_all,
               unsigned short* __restrict__ qk, unsigned short* __restrict__ vp) {
    __shared__ float Tl[64][65];                           // 16.6 KB transpose tile
    __shared__ __align__(16) unsigned short Xl[64][264];   // 33.8 KB, stride 264

    int n0   = blockIdx.x * 64;
    int b    = blockIdx.y;
    int tid  = threadIdx.x;
    int lane = tid & 63;
    int w    = tid >> 6;
    int col  = lane & 15;
    int quad = lane >> 4;

    // stage: x[b][c0+c][n0..n0+63] fp32 -> Xl[n][c0+c] bf16, 4 passes of 64 ch
    for (int c0 = 0; c0 < CH; c0 += 64) {
        if (c0) __syncthreads();
#pragma unroll
        for (int r = 0; r < 4; ++r) {
            int f  = r * 256 + tid;
            int c  = f >> 4;
            int n4 = f & 15;
            float4 v = *(const float4*)(x + ((size_t)b * CH + c0 + c) * NPIX + n0 + n4 * 4);
            Tl[n4 * 4 + 0][c] = v.x;
            Tl[n4 * 4 + 1][c] = v.y;
            Tl[n4 * 4 + 2][c] = v.z;
            Tl[n4 * 4 + 3][c] = v.w;
        }
        __syncthreads();
#pragma unroll
        for (int r = 0; r < 2; ++r) {
            int f    = r * 256 + tid;
            int nrow = f >> 3;
            int c8   = f & 7;
            unsigned int pk[4];
#pragma unroll
            for (int p = 0; p < 4; ++p) {
                unsigned int lo = f2bf(Tl[nrow][c8 * 8 + p * 2 + 0]);
                unsigned int hi = f2bf(Tl[nrow][c8 * 8 + p * 2 + 1]);
                pk[p] = lo | (hi << 16);
            }
            *(uint4*)&Xl[nrow][c0 + c8 * 8] = *(uint4*)pk;
        }
    }
    __syncthreads();

#pragma unroll
    for (int og = 0; og < 6; ++og) {
        int o0 = og * 64;
        // fragment-ordered A base for (og, w): 8 kc x 64 lanes x 8 bf16
        const unsigned short* Af = W_frag + ((size_t)(og * 32 + w * 8) << 9);

        f32x4 acc[4];
#pragma unroll
        for (int t = 0; t < 4; ++t) acc[t] = (f32x4){0.f, 0.f, 0.f, 0.f};

#pragma unroll
        for (int kc = 0; kc < 8; ++kc) {
            short8 a = *(const short8*)(Af + ((kc << 6) + lane) * 8);   // coalesced
#pragma unroll
            for (int nt = 0; nt < 4; ++nt) {
                short8 bb = *(const short8*)&Xl[nt * 16 + col][kc * 32 + quad * 8];
                acc[nt] = MFMA16x16(a, bb, acc[nt]);
            }
        }

        float4 bias = *(const float4*)(bias_all + o0 + w * 16 + quad * 4);
        float bs[4] = {bias.x, bias.y, bias.z, bias.w};

        if (og < 2) {
#pragma unroll
            for (int nt = 0; nt < 4; ++nt) {
                int n = n0 + nt * 16 + col;
                unsigned int pk[2];
#pragma unroll
                for (int p = 0; p < 2; ++p) {
                    unsigned int lo = f2bf(acc[nt][p * 2 + 0] + bs[p * 2 + 0]);
                    unsigned int hi = f2bf(acc[nt][p * 2 + 1] + bs[p * 2 + 1]);
                    pk[p] = lo | (hi << 16);
                }
                *(uint2*)(qk + ((size_t)b * NPIX + n) * 128 + o0 + w * 16 + quad * 4) = *(uint2*)pk;
            }
        } else {
#pragma unroll
            for (int nt = 0; nt < 4; ++nt) {
                int n = n0 + nt * 16 + col;
#pragma unroll
                for (int r = 0; r < 4; ++r) {
                    int oo = o0 - 128 + w * 16 + quad * 4 + r;
                    vp[((size_t)b * CH + oo) * NPIX + n] = f2bf(acc[nt][r] + bs[r]);
                }
            }
        }
    }
}

// ---------------------------------------------------------------------------
// Kernel A v12: v11 skeleton (1 barrier/iter, dbuf Qt+St, depth-1 prefetch)
// with phase-B wave remap og(w>>1) x jg(w&1): wave owns 64 o x 32 j
// (acc[4][2], same 32 regs). St reads HALVE (each wave reads only its 32-j
// half): LDS 112 -> 80 KB/block-iter. V rows read by 2 waves (jg pair,
// back-to-back -> L1). V prefetch split (ks0 depth-1 in vbn0; ks1 refilled
// in-place post-B) to stay under the 128-VGPR 4-wave/SIMD cliff.
// Phase A unchanged from v6/v11. LDS 36.9 KB; 2 blocks/CU; XCD swizzle.
// ---------------------------------------------------------------------------
#define LPK 72
__global__ __launch_bounds__(512, 4)
void attn_v12(const unsigned short* __restrict__ qk,   // [B][N][128]: q=0..63, k=64..127
              const unsigned short* __restrict__ vp,   // [B][256][N]
              const float* __restrict__ bg, float* __restrict__ out) {
    __shared__ __align__(16) unsigned short Qt[2][64][LPK];   // [buf][i][ch] 18.4 KB
    __shared__ __align__(16) unsigned short St[2][64][LPK];   // [buf][j][i]  18.4 KB

    int lin  = blockIdx.y * gridDim.x + blockIdx.x;
    int b    = lin & 7;                 // XCD-swizzle: one batch per XCD
    int j0   = (lin >> 3) * 64;
    int tid  = threadIdx.x;
    int lane = tid & 63;
    int w    = tid >> 6;
    int col  = lane & 15;
    int quad = lane >> 4;

    int tjA = w & 3;              // phase-A j-tile
    int tiP = (w >> 2) * 2;       // phase-A i-tile pair
    int og  = w >> 1;             // phase-B o-group (0..3): 64 o
    int jg  = w & 1;              // phase-B j-group (0..1): 32 j

    // iteration-invariant K fragments (phase A; B-operand: n=j, k=ch)
    short8 bK[2];
#pragma unroll
    for (int ks = 0; ks < 2; ++ks)
        bK[ks] = *(const short8*)(qk + ((size_t)b * NPIX + j0 + tjA * 16 + col) * 128 + 64 + ks * 32 + quad * 8);

    f32x4 acc[4][2];   // [o-tile][j-tile]; D: col=o, rows=j
#pragma unroll
    for (int ot = 0; ot < 4; ++ot)
#pragma unroll
        for (int tj = 0; tj < 2; ++tj) acc[ot][tj] = (f32x4){0.f, 0.f, 0.f, 0.f};

    // staging coords (v6-identical coalesced patterns)
    int qrow = tid >> 3, q8 = tid & 7;
    const unsigned short* Qsrc = qk + ((size_t)b * NPIX + qrow) * 128 + q8 * 8;
    const unsigned short* Vsrc[4];
#pragma unroll
    for (int ot = 0; ot < 4; ++ot)
        Vsrc[ot] = vp + ((size_t)b * CH + og * 64 + ot * 16 + col) * NPIX + quad * 8;

    const float invN = 1.f / (float)NPIX;

    // ---- prologue ----
    {
        uint4 q0 = *(const uint4*)Qsrc;
        *(uint4*)&Qt[0][qrow][q8 * 8] = q0;
    }
    uint4 qrA = *(const uint4*)(Qsrc + (size_t)64 * 128);   // Q(1)
    short8 vb0[4], vb1[4], vbn0[4];
#pragma unroll
    for (int ot = 0; ot < 4; ++ot) {
        vb0[ot] = *(const short8*)(Vsrc[ot]);        // V(0) ks0
        vb1[ot] = *(const short8*)(Vsrc[ot] + 32);   // V(0) ks1
    }

    __syncthreads();   // Qt[0] visible

    // A(0): Qt[0] -> St[0]
#pragma unroll
    for (int t = 0; t < 2; ++t) {
        int ti = tiP + t;
        short8 a0 = *(const short8*)&Qt[0][ti * 16 + col][quad * 8];
        short8 a1 = *(const short8*)&Qt[0][ti * 16 + col][32 + quad * 8];
        f32x4 s = (f32x4){0.f, 0.f, 0.f, 0.f};
        s = MFMA16x16(a0, bK[0], s);
        s = MFMA16x16(a1, bK[1], s);
        unsigned int pk2[2];
#pragma unroll
        for (int pp = 0; pp < 2; ++pp) {
            float e0 = s[pp * 2 + 0];
            float e1 = s[pp * 2 + 1];
            float g0 = __expf(e0) - 1.f;
            float g1 = __expf(e1) - 1.f;
            e0 = (e0 > 0.f) ? e0 : g0;
            e1 = (e1 > 0.f) ? e1 : g1;
            e0 *= invN;
            e1 *= invN;
            unsigned int rpk;
            asm("v_cvt_pk_bf16_f32 %0, %1, %2" : "=v"(rpk) : "v"(e0), "v"(e1));
            pk2[pp] = rpk;
        }
        *(uint2*)&St[0][tjA * 16 + col][ti * 16 + quad * 4] = *(uint2*)pk2;
    }
    *(uint4*)&Qt[1][qrow][q8 * 8] = qrA;                    // stage Q(1)
    qrA = *(const uint4*)(Qsrc + (size_t)(2 * 64) * 128);   // Q(2)

    // ---- main loop: body it handles B(it-1) and A(it) ----
    for (int it = 1; it < NPIX / 64; ++it) {
        int pw = it & 1;            // A reads Qt[pw], writes St[pw]

        __syncthreads();            // one barrier per iteration

        // stage Qt[pw^1] = Q(it+1); prefetch Q(it+2)
        *(uint4*)&Qt[pw ^ 1][qrow][q8 * 8] = qrA;
        {
            size_t iq = (size_t)(((it + 2) * 64) & (NPIX - 1));
            qrA = *(const uint4*)(Qsrc + iq * 128);
        }
        // prefetch V(it) ks0 (consumed next body)
        int iv = it * 64;
#pragma unroll
        for (int ot = 0; ot < 4; ++ot)
            vbn0[ot] = *(const short8*)(Vsrc[ot] + iv);

        // ---- phase B(it-1): acc += S(St[pw^1], own 32 j) x V(vb = V(it-1)) ----
#pragma unroll
        for (int ks = 0; ks < 2; ++ks) {
            short8 sb[2];
#pragma unroll
            for (int tj = 0; tj < 2; ++tj)
                sb[tj] = *(const short8*)&St[pw ^ 1][jg * 32 + tj * 16 + col][ks * 32 + quad * 8];
            __builtin_amdgcn_s_setprio(1);
#pragma unroll
            for (int ot = 0; ot < 4; ++ot) {
                short8 v = (ks == 0) ? vb0[ot] : vb1[ot];
#pragma unroll
                for (int tj = 0; tj < 2; ++tj)
                    acc[ot][tj] = MFMA16x16(sb[tj], v, acc[ot][tj]);
            }
            __builtin_amdgcn_s_setprio(0);
        }

        // refill V(it) ks1 in place (vb1 dead after B; consumed next body)
#pragma unroll
        for (int ot = 0; ot < 4; ++ot)
            vb1[ot] = *(const short8*)(Vsrc[ot] + iv + 32);

        // ---- phase A(it): Qt[pw] -> St[pw] ----
#pragma unroll
        for (int t = 0; t < 2; ++t) {
            int ti = tiP + t;
            short8 a0 = *(const short8*)&Qt[pw][ti * 16 + col][quad * 8];
            short8 a1 = *(const short8*)&Qt[pw][ti * 16 + col][32 + quad * 8];
            f32x4 s = (f32x4){0.f, 0.f, 0.f, 0.f};
            s = MFMA16x16(a0, bK[0], s);
            s = MFMA16x16(a1, bK[1], s);
            unsigned int pk2[2];
#pragma unroll
            for (int pp = 0; pp < 2; ++pp) {
                float e0 = s[pp * 2 + 0];
                float e1 = s[pp * 2 + 1];
                float g0 = __expf(e0) - 1.f;
                float g1 = __expf(e1) - 1.f;
                e0 = (e0 > 0.f) ? e0 : g0;
                e1 = (e1 > 0.f) ? e1 : g1;
                e0 *= invN;
                e1 *= invN;
                unsigned int rpk;
                asm("v_cvt_pk_bf16_f32 %0, %1, %2" : "=v"(rpk) : "v"(e0), "v"(e1));
                pk2[pp] = rpk;
            }
            *(uint2*)&St[pw][tjA * 16 + col][ti * 16 + quad * 4] = *(uint2*)pk2;
        }

        // rotate ks0 prefetch
#pragma unroll
        for (int ot = 0; ot < 4; ++ot)
            vb0[ot] = vbn0[ot];
    }

    // ---- epilogue: B(63): St[1], vb = V(63) ----
    __syncthreads();
#pragma unroll
    for (int ks = 0; ks < 2; ++ks) {
        short8 sb[2];
#pragma unroll
        for (int tj = 0; tj < 2; ++tj)
            sb[tj] = *(const short8*)&St[1][jg * 32 + tj * 16 + col][ks * 32 + quad * 8];
#pragma unroll
        for (int ot = 0; ot < 4; ++ot) {
            short8 v = (ks == 0) ? vb0[ot] : vb1[ot];
#pragma unroll
            for (int tj = 0; tj < 2; ++tj)
                acc[ot][tj] = MFMA16x16(sb[tj], v, acc[ot][tj]);
        }
    }

    // epilogue stores: D col=o, rows=4 consecutive j -> float4
#pragma unroll
    for (int ot = 0; ot < 4; ++ot) {
        int o = og * 64 + ot * 16 + col;
        float bgv = bg[o];
#pragma unroll
        for (int tj = 0; tj < 2; ++tj) {
            int j = j0 + jg * 32 + tj * 16 + quad * 4;
            float4 st;
            st.x = acc[ot][tj][0] + bgv;
            st.y = acc[ot][tj][1] + bgv;
            st.z = acc[ot][tj][2] + bgv;
            st.w = acc[ot][tj][3] + bgv;
            *(float4*)&out[((size_t)b * CH + o) * NPIX + j] = st;
        }
    }
}

// ---------------------------------------------------------------------------
extern "C" void kernel_launch(void* const* d_in, const int* in_sizes, int n_in,
                              void* d_out, int out_size, void* d_ws, size_t ws_size,
                              hipStream_t stream) {
    const float* x  = (const float*)d_in[0];
    const float* wq = (const float*)d_in[1];
    const float* bq = (const float*)d_in[2];
    const float* wk = (const float*)d_in[3];
    const float* bk = (const float*)d_in[4];
    const float* wv = (const float*)d_in[5];
    const float* bv = (const float*)d_in[6];
    const float* wg = (const float*)d_in[7];
    const float* bg = (const float*)d_in[8];
    float* out = (float*)d_out;

    unsigned short* W_frag = (unsigned short*)d_ws;
    float* bias_all = (float*)(W_frag + 384 * 256);
    unsigned short* qk = (unsigned short*)(bias_all + 384);
    unsigned short* vp = qk + (size_t)BATCH * NPIX * 128;

    prep_kernel<<<dim3(384), dim3(256), 0, stream>>>(wq, bq, wk, bk, wv, bv, wg, W_frag, bias_all);
    qkvf_mfma<<<dim3(NPIX / 64, BATCH), dim3(256), 0, stream>>>(x, W_frag, bias_all, qk, vp);
    attn_v12<<<dim3(NPIX / 64, BATCH), dim3(512), 0, stream>>>(qk, vp, bg, out);
}

// Round 9
// 244.269 us; speedup vs baseline: 1.4619x; 1.4619x over previous
//
#include <hip/hip_runtime.h>
#include <math.h>

#define BATCH 8
#define CH    256
#define NPIX  4096
#define CKDIM 64

typedef __attribute__((ext_vector_type(8))) short short8;   // 8 bf16 (4 VGPRs)
typedef __attribute__((ext_vector_type(4))) float f32x4;    // MFMA accumulator

#define MFMA16x16(a, b, c) __builtin_amdgcn_mfma_f32_16x16x32_bf16((a), (b), (c), 0, 0, 0)

__device__ __forceinline__ unsigned short f2bf(float f) {
    union { float f; unsigned int u; } v; v.f = f;
    unsigned int u = v.u;
    u += 0x7fffu + ((u >> 16) & 1u);      // round-to-nearest-even
    return (unsigned short)(u >> 16);
}

// ---------------------------------------------------------------------------
// Kernel P (round-8 proven): W_frag in MFMA-fragment order + bias_all[384].
// Element (o,c) -> idx = (((og*4+w)*8+kc)*64 + quad*16 + col)*8 + e
// so qkvf's per-wave A-operand load is one coalesced 1KB line.
// ---------------------------------------------------------------------------
__global__ void prep_kernel(const float* __restrict__ wq, const float* __restrict__ bq,
                            const float* __restrict__ wk, const float* __restrict__ bk,
                            const float* __restrict__ wv, const float* __restrict__ bv,
                            const float* __restrict__ wg,
                            unsigned short* __restrict__ W_frag, float* __restrict__ bias_all) {
    int o = blockIdx.x;
    int c = threadIdx.x;

    float val;
    if (o < 64) {
        val = wq[o * CH + c];
        if (c == 0) bias_all[o] = bq[o];
    } else if (o < 128) {
        int oo = o - 64;
        val = wk[oo * CH + c];
        if (c == 0) bias_all[o] = bk[oo];
    } else {
        __shared__ float wgr[CH];
        int oo = o - 128;
        wgr[c] = wg[oo * CH + c];
        __syncthreads();
        float a0 = 0.f, a1 = 0.f, a2 = 0.f, a3 = 0.f;
#pragma unroll 4
        for (int m = 0; m < CH; m += 4) {
            a0 += wgr[m + 0] * wv[(m + 0) * CH + c];
            a1 += wgr[m + 1] * wv[(m + 1) * CH + c];
            a2 += wgr[m + 2] * wv[(m + 2) * CH + c];
            a3 += wgr[m + 3] * wv[(m + 3) * CH + c];
        }
        val = (a0 + a1) + (a2 + a3);
        if (c == 0) {
            float b = 0.f;
            for (int m = 0; m < CH; ++m) b += wgr[m] * bv[m];
            bias_all[o] = b;
        }
    }

    int og = o >> 6, w = (o >> 4) & 3, col = o & 15;
    int kc = c >> 5, quad = (c >> 3) & 3, e = c & 7;
    size_t idx = ((size_t)(((og * 4 + w) * 8 + kc) * 64 + quad * 16 + col)) * 8 + e;
    W_frag[idx] = f2bf(val);
}

// ---------------------------------------------------------------------------
// Kernel G' (round-8 proven): FUSED xpose+qkv, fragment-ordered W A-loads
// (coalesced, L2-hot), 3 blocks/CU.
// ---------------------------------------------------------------------------
__global__ __launch_bounds__(256, 3)
void qkvf_mfma(const float* __restrict__ x,
               const unsigned short* __restrict__ W_frag,
               const float* __restrict__ bias_all,
               unsigned short* __restrict__ qk, unsigned short* __restrict__ vp) {
    __shared__ float Tl[64][65];                           // 16.6 KB transpose tile
    __shared__ __align__(16) unsigned short Xl[64][264];   // 33.8 KB, stride 264

    int n0   = blockIdx.x * 64;
    int b    = blockIdx.y;
    int tid  = threadIdx.x;
    int lane = tid & 63;
    int w    = tid >> 6;
    int col  = lane & 15;
    int quad = lane >> 4;

    // stage: x[b][c0+c][n0..n0+63] fp32 -> Xl[n][c0+c] bf16, 4 passes of 64 ch
    for (int c0 = 0; c0 < CH; c0 += 64) {
        if (c0) __syncthreads();
#pragma unroll
        for (int r = 0; r < 4; ++r) {
            int f  = r * 256 + tid;
            int c  = f >> 4;
            int n4 = f & 15;
            float4 v = *(const float4*)(x + ((size_t)b * CH + c0 + c) * NPIX + n0 + n4 * 4);
            Tl[n4 * 4 + 0][c] = v.x;
            Tl[n4 * 4 + 1][c] = v.y;
            Tl[n4 * 4 + 2][c] = v.z;
            Tl[n4 * 4 + 3][c] = v.w;
        }
        __syncthreads();
#pragma unroll
        for (int r = 0; r < 2; ++r) {
            int f    = r * 256 + tid;
            int nrow = f >> 3;
            int c8   = f & 7;
            unsigned int pk[4];
#pragma unroll
            for (int p = 0; p < 4; ++p) {
                unsigned int lo = f2bf(Tl[nrow][c8 * 8 + p * 2 + 0]);
                unsigned int hi = f2bf(Tl[nrow][c8 * 8 + p * 2 + 1]);
                pk[p] = lo | (hi << 16);
            }
            *(uint4*)&Xl[nrow][c0 + c8 * 8] = *(uint4*)pk;
        }
    }
    __syncthreads();

#pragma unroll
    for (int og = 0; og < 6; ++og) {
        int o0 = og * 64;
        const unsigned short* Af = W_frag + ((size_t)(og * 32 + w * 8) << 9);

        f32x4 acc[4];
#pragma unroll
        for (int t = 0; t < 4; ++t) acc[t] = (f32x4){0.f, 0.f, 0.f, 0.f};

#pragma unroll
        for (int kc = 0; kc < 8; ++kc) {
            short8 a = *(const short8*)(Af + ((kc << 6) + lane) * 8);   // coalesced
#pragma unroll
            for (int nt = 0; nt < 4; ++nt) {
                short8 bb = *(const short8*)&Xl[nt * 16 + col][kc * 32 + quad * 8];
                acc[nt] = MFMA16x16(a, bb, acc[nt]);
            }
        }

        float4 bias = *(const float4*)(bias_all + o0 + w * 16 + quad * 4);
        float bs[4] = {bias.x, bias.y, bias.z, bias.w};

        if (og < 2) {
#pragma unroll
            for (int nt = 0; nt < 4; ++nt) {
                int n = n0 + nt * 16 + col;
                unsigned int pk[2];
#pragma unroll
                for (int p = 0; p < 2; ++p) {
                    unsigned int lo = f2bf(acc[nt][p * 2 + 0] + bs[p * 2 + 0]);
                    unsigned int hi = f2bf(acc[nt][p * 2 + 1] + bs[p * 2 + 1]);
                    pk[p] = lo | (hi << 16);
                }
                *(uint2*)(qk + ((size_t)b * NPIX + n) * 128 + o0 + w * 16 + quad * 4) = *(uint2*)pk;
            }
        } else {
#pragma unroll
            for (int nt = 0; nt < 4; ++nt) {
                int n = n0 + nt * 16 + col;
#pragma unroll
                for (int r = 0; r < 4; ++r) {
                    int oo = o0 - 128 + w * 16 + quad * 4 + r;
                    vp[((size_t)b * CH + oo) * NPIX + n] = f2bf(acc[nt][r] + bs[r]);
                }
            }
        }
    }
}

// ---------------------------------------------------------------------------
// Kernel A v11 (round-7 proven VERBATIM: 149.1 us, MfmaUtil 24.1, VGPR 56).
// 1 barrier/iter via dbuf Qt+St; body(t): BAR -> stage Qt -> prefetch ->
// B(t-1) -> A(t). v6 coalesced/depth-1 load patterns byte-identical.
// LDS 36.9 KB; 2 blocks/CU; XCD swizzle (one batch per XCD).
// ---------------------------------------------------------------------------
#define LPK 72
__global__ __launch_bounds__(512, 4)
void attn_v11(const unsigned short* __restrict__ qk,   // [B][N][128]: q=0..63, k=64..127
              const unsigned short* __restrict__ vp,   // [B][256][N]
              const float* __restrict__ bg, float* __restrict__ out) {
    __shared__ __align__(16) unsigned short Qt[2][64][LPK];   // [buf][i][ch] 18.4 KB
    __shared__ __align__(16) unsigned short St[2][64][LPK];   // [buf][j][i]  18.4 KB

    int lin  = blockIdx.y * gridDim.x + blockIdx.x;
    int b    = lin & 7;                 // XCD-swizzle: one batch per XCD
    int j0   = (lin >> 3) * 64;
    int tid  = threadIdx.x;
    int lane = tid & 63;
    int w    = tid >> 6;
    int col  = lane & 15;
    int quad = lane >> 4;

    int tjA = w & 3;              // phase-A j-tile (this wave's K column block)
    int tiP = (w >> 2) * 2;       // phase-A i-tile pair

    // iteration-invariant K fragments (global, once; B-operand: n=j, k=ch)
    short8 bK[2];
#pragma unroll
    for (int ks = 0; ks < 2; ++ks)
        bK[ks] = *(const short8*)(qk + ((size_t)b * NPIX + j0 + tjA * 16 + col) * 128 + 64 + ks * 32 + quad * 8);

    f32x4 acc[2][4];   // [o-tile][j-tile]; D: col=o, rows=j
#pragma unroll
    for (int ot = 0; ot < 2; ++ot)
#pragma unroll
        for (int tj = 0; tj < 4; ++tj) acc[ot][tj] = (f32x4){0.f, 0.f, 0.f, 0.f};

    // per-thread staging coords (v6-identical coalesced patterns)
    int qrow = tid >> 3, q8 = tid & 7;
    const unsigned short* Qsrc = qk + ((size_t)b * NPIX + qrow) * 128 + q8 * 8;
    const unsigned short* Vsrc[2];
#pragma unroll
    for (int ot = 0; ot < 2; ++ot)
        Vsrc[ot] = vp + ((size_t)b * CH + (w * 2 + ot) * 16 + col) * NPIX + quad * 8;

    const float invN = 1.f / (float)NPIX;

    // ---- prologue ----
    {
        uint4 q0 = *(const uint4*)Qsrc;
        *(uint4*)&Qt[0][qrow][q8 * 8] = q0;
    }
    uint4 qrA = *(const uint4*)(Qsrc + (size_t)64 * 128);   // Q(1)
    short8 vb[2][2];
#pragma unroll
    for (int ot = 0; ot < 2; ++ot)
#pragma unroll
        for (int ks = 0; ks < 2; ++ks)
            vb[ot][ks] = *(const short8*)(Vsrc[ot] + ks * 32);   // V(0)

    __syncthreads();   // Qt[0] visible

    // A(0): Qt[0] -> St[0]
#pragma unroll
    for (int t = 0; t < 2; ++t) {
        int ti = tiP + t;
        short8 a0 = *(const short8*)&Qt[0][ti * 16 + col][quad * 8];
        short8 a1 = *(const short8*)&Qt[0][ti * 16 + col][32 + quad * 8];
        f32x4 s = (f32x4){0.f, 0.f, 0.f, 0.f};
        s = MFMA16x16(a0, bK[0], s);
        s = MFMA16x16(a1, bK[1], s);
        unsigned int pk2[2];
#pragma unroll
        for (int pp = 0; pp < 2; ++pp) {
            float e0 = s[pp * 2 + 0];
            float e1 = s[pp * 2 + 1];
            float g0 = __expf(e0) - 1.f;
            float g1 = __expf(e1) - 1.f;
            e0 = (e0 > 0.f) ? e0 : g0;
            e1 = (e1 > 0.f) ? e1 : g1;
            e0 *= invN;
            e1 *= invN;
            unsigned int rpk;
            asm("v_cvt_pk_bf16_f32 %0, %1, %2" : "=v"(rpk) : "v"(e0), "v"(e1));
            pk2[pp] = rpk;
        }
        *(uint2*)&St[0][tjA * 16 + col][ti * 16 + quad * 4] = *(uint2*)pk2;
    }
    // stage Qt[1] = Q(1); prefetch Q(2)
    *(uint4*)&Qt[1][qrow][q8 * 8] = qrA;
    qrA = *(const uint4*)(Qsrc + (size_t)(2 * 64) * 128);   // Q(2)

    // ---- main loop: body it handles B(it-1) and A(it) ----
    for (int it = 1; it < NPIX / 64; ++it) {
        int pw = it & 1;            // A reads Qt[pw], writes St[pw]

        __syncthreads();            // one barrier per iteration

        // stage Qt[pw^1] = Q(it+1) (regs loaded last body)
        *(uint4*)&Qt[pw ^ 1][qrow][q8 * 8] = qrA;

        // issue prefetches: Q(it+2) [wraps harmlessly], V(it)
        {
            size_t iq = (size_t)(((it + 2) * 64) & (NPIX - 1));
            qrA = *(const uint4*)(Qsrc + iq * 128);
        }
        int iv = it * 64;
        short8 vb_n[2][2];
#pragma unroll
        for (int ot = 0; ot < 2; ++ot)
#pragma unroll
            for (int ks = 0; ks < 2; ++ks)
                vb_n[ot][ks] = *(const short8*)(Vsrc[ot] + iv + ks * 32);

        // ---- phase B(it-1): acc += S(St[pw^1]) x V(vb = V(it-1)) ----
#pragma unroll
        for (int ks = 0; ks < 2; ++ks) {
            short8 sb[4];
#pragma unroll
            for (int tj = 0; tj < 4; ++tj)
                sb[tj] = *(const short8*)&St[pw ^ 1][tj * 16 + col][ks * 32 + quad * 8];
            __builtin_amdgcn_s_setprio(1);
#pragma unroll
            for (int ot = 0; ot < 2; ++ot)
#pragma unroll
                for (int tj = 0; tj < 4; ++tj)
                    acc[ot][tj] = MFMA16x16(sb[tj], vb[ot][ks], acc[ot][tj]);
            __builtin_amdgcn_s_setprio(0);
        }

        // ---- phase A(it): Qt[pw] -> St[pw] ----
#pragma unroll
        for (int t = 0; t < 2; ++t) {
            int ti = tiP + t;
            short8 a0 = *(const short8*)&Qt[pw][ti * 16 + col][quad * 8];
            short8 a1 = *(const short8*)&Qt[pw][ti * 16 + col][32 + quad * 8];
            f32x4 s = (f32x4){0.f, 0.f, 0.f, 0.f};
            s = MFMA16x16(a0, bK[0], s);
            s = MFMA16x16(a1, bK[1], s);
            unsigned int pk2[2];
#pragma unroll
            for (int pp = 0; pp < 2; ++pp) {
                float e0 = s[pp * 2 + 0];
                float e1 = s[pp * 2 + 1];
                float g0 = __expf(e0) - 1.f;
                float g1 = __expf(e1) - 1.f;
                e0 = (e0 > 0.f) ? e0 : g0;
                e1 = (e1 > 0.f) ? e1 : g1;
                e0 *= invN;
                e1 *= invN;
                unsigned int rpk;
                asm("v_cvt_pk_bf16_f32 %0, %1, %2" : "=v"(rpk) : "v"(e0), "v"(e1));
                pk2[pp] = rpk;
            }
            *(uint2*)&St[pw][tjA * 16 + col][ti * 16 + quad * 4] = *(uint2*)pk2;
        }

        // rotate V regs (vb <- V(it))
#pragma unroll
        for (int ot = 0; ot < 2; ++ot)
#pragma unroll
            for (int ks = 0; ks < 2; ++ks)
                vb[ot][ks] = vb_n[ot][ks];
    }

    // ---- epilogue: B(63): St[1], vb = V(63) ----
    __syncthreads();
#pragma unroll
    for (int ks = 0; ks < 2; ++ks) {
        short8 sb[4];
#pragma unroll
        for (int tj = 0; tj < 4; ++tj)
            sb[tj] = *(const short8*)&St[1][tj * 16 + col][ks * 32 + quad * 8];
#pragma unroll
        for (int ot = 0; ot < 2; ++ot)
#pragma unroll
            for (int tj = 0; tj < 4; ++tj)
                acc[ot][tj] = MFMA16x16(sb[tj], vb[ot][ks], acc[ot][tj]);
    }

    // epilogue: D col=o, rows=4 consecutive j -> float4 stores
#pragma unroll
    for (int ot = 0; ot < 2; ++ot) {
        int o = (w * 2 + ot) * 16 + col;
        float bgv = bg[o];
#pragma unroll
        for (int tj = 0; tj < 4; ++tj) {
            int j = j0 + tj * 16 + quad * 4;
            float4 st;
            st.x = acc[ot][tj][0] + bgv;
            st.y = acc[ot][tj][1] + bgv;
            st.z = acc[ot][tj][2] + bgv;
            st.w = acc[ot][tj][3] + bgv;
            *(float4*)&out[((size_t)b * CH + o) * NPIX + j] = st;
        }
    }
}

// ---------------------------------------------------------------------------
extern "C" void kernel_launch(void* const* d_in, const int* in_sizes, int n_in,
                              void* d_out, int out_size, void* d_ws, size_t ws_size,
                              hipStream_t stream) {
    const float* x  = (const float*)d_in[0];
    const float* wq = (const float*)d_in[1];
    const float* bq = (const float*)d_in[2];
    const float* wk = (const float*)d_in[3];
    const float* bk = (const float*)d_in[4];
    const float* wv = (const float*)d_in[5];
    const float* bv = (const float*)d_in[6];
    const float* wg = (const float*)d_in[7];
    const float* bg = (const float*)d_in[8];
    float* out = (float*)d_out;

    unsigned short* W_frag = (unsigned short*)d_ws;
    float* bias_all = (float*)(W_frag + 384 * 256);
    unsigned short* qk = (unsigned short*)(bias_all + 384);
    unsigned short* vp = qk + (size_t)BATCH * NPIX * 128;

    prep_kernel<<<dim3(384), dim3(256), 0, stream>>>(wq, bq, wk, bk, wv, bv, wg, W_frag, bias_all);
    qkvf_mfma<<<dim3(NPIX / 64, BATCH), dim3(256), 0, stream>>>(x, W_frag, bias_all, qk, vp);
    attn_v11<<<dim3(NPIX / 64, BATCH), dim3(512), 0, stream>>>(qk, vp, bg, out);
}